// Round 9
// baseline (184.909 us; speedup 1.0000x reference)
//
#include <hip/hip_runtime.h>

#define N_NODES 10000
#define NFEAT   512
#define NHID    256
#define NHID2   128
#define CAP     128   // max nnz/row stored; binomial(10000,0.005) mean 50, sd 7 -> 128 is >11 sigma

typedef __attribute__((ext_vector_type(8))) short bf16x8;
typedef __attribute__((ext_vector_type(4))) float f32x4;
typedef __attribute__((ext_vector_type(2))) int   i32x2;

__device__ __forceinline__ ushort f2bf(float f){
  union { float f; unsigned u; } v; v.f = f;
  unsigned r = v.u + 0x7FFFu + ((v.u >> 16) & 1u);   // round-to-nearest-even
  return (ushort)(r >> 16);
}
__device__ __forceinline__ float bf2f(ushort u){
  union { unsigned u; float f; } v; v.u = ((unsigned)u) << 16; return v.f;
}

// ---- K0: bf16 converts (x -> xb, W1 -> W1t, W2 -> W2t) ----
__global__ void k_cvt(const float* __restrict__ x, const float* __restrict__ W1,
                      const float* __restrict__ W2, ushort* __restrict__ xb,
                      ushort* __restrict__ w1t, ushort* __restrict__ w2t){
  const int b = blockIdx.x, t = threadIdx.x;
  if (b < 5000){                       // x: 4 elems/thread, exact grid
    int i = (b * 256 + t) * 4;
    float4 q = *(const float4*)(x + i);
    ushort4 o; o.x = f2bf(q.x); o.y = f2bf(q.y); o.z = f2bf(q.z); o.w = f2bf(q.w);
    *(ushort4*)(xb + i) = o;
  } else if (b < 5512){                // W1t[n][k] = W1[k][n]
    int id = (b - 5000) * 256 + t;
    int n = id >> 9, k = id & 511;
    w1t[id] = f2bf(W1[k * NHID + n]);
  } else {                             // W2t[n][k] = W2[k][n]
    int id = (b - 5512) * 256 + t;
    int n = id >> 8, k = id & 255;
    w2t[id] = f2bf(W2[k * NHID2 + n]);
  }
}

// ---- K1: gemm1 (blocks 0..627) fused with adj scan (blocks 628..10627) ----
__launch_bounds__(256)
__global__ void k_scan_gemm1(const float* __restrict__ adj, const ushort* __restrict__ xb,
                             const ushort* __restrict__ w1t, ushort* __restrict__ xw1_lo,
                             ushort* __restrict__ xw1_hi, int* __restrict__ row_nnz,
                             i32x2* __restrict__ pja){
  const int b = blockIdx.x, t = threadIdx.x;
  const int lane = t & 63, w = t >> 6;

  if (b < 628){
    // ---- gemm1 path: 64x64 tile, WR=WC=2, K=512 ----
    const int bx = b % 157, by = b / 157;
    const int wr = w >> 1, wc = w & 1;
    const int r16 = lane & 15, kg = lane >> 4;
    const int row0 = bx * 64 + wr * 32;
    const int col0 = by * 64 + wc * 32;

    int arow[2], bcol[2];
    #pragma unroll
    for (int r = 0; r < 2; r++){
      int ar = row0 + r * 16 + r16;
      arow[r] = (ar >= N_NODES) ? (N_NODES - 1) : ar;
    }
    #pragma unroll
    for (int c = 0; c < 2; c++) bcol[c] = col0 + c * 16 + r16;

    f32x4 acc[2][2];
    #pragma unroll
    for (int r = 0; r < 2; r++)
      #pragma unroll
      for (int c = 0; c < 2; c++)
        acc[r][c] = (f32x4){0.f, 0.f, 0.f, 0.f};

    bf16x8 aA[2], bA[2], aB[2], bB[2];
    auto LOADF = [&](bf16x8* a, bf16x8* bb, int k0){
      #pragma unroll
      for (int r = 0; r < 2; r++)
        a[r] = *(const bf16x8*)(xb + (size_t)arow[r] * NFEAT + k0 + kg * 8);
      #pragma unroll
      for (int c = 0; c < 2; c++)
        bb[c] = *(const bf16x8*)(w1t + (size_t)bcol[c] * NFEAT + k0 + kg * 8);
    };
    auto MM = [&](bf16x8* a, bf16x8* bb){
      #pragma unroll
      for (int r = 0; r < 2; r++)
        #pragma unroll
        for (int c = 0; c < 2; c++)
          acc[r][c] = __builtin_amdgcn_mfma_f32_16x16x32_bf16(a[r], bb[c], acc[r][c], 0, 0, 0);
    };

    LOADF(aA, bA, 0);
    #pragma unroll
    for (int k0 = 0; k0 < NFEAT; k0 += 64){
      if (k0 + 32 < NFEAT) LOADF(aB, bB, k0 + 32);
      MM(aA, bA);
      if (k0 + 64 < NFEAT) LOADF(aA, bA, k0 + 64);
      if (k0 + 32 < NFEAT) MM(aB, bB);
    }

    ushort* dst = (by < 2) ? xw1_lo : xw1_hi;
    const int cbase = (by < 2) ? 0 : 128;
    #pragma unroll
    for (int r = 0; r < 2; r++)
      #pragma unroll
      for (int c = 0; c < 2; c++){
        int col = col0 + c * 16 + r16 - cbase;
        #pragma unroll
        for (int i = 0; i < 4; i++){
          int row = row0 + r * 16 + kg * 4 + i;
          if (row < N_NODES) dst[(size_t)row * 128 + col] = f2bf(acc[r][c][i]);
        }
      }
    return;
  }

  // ---- scan path: row r, single nontemporal pass, register-cached ----
  const int r = b - 628;
  const float* row = adj + (size_t)r * N_NODES;
  __shared__ int swave[4];

  f32x4 vals[10];
  #pragma unroll
  for (int v = 0; v < 9; v++)
    vals[v] = __builtin_nontemporal_load((const f32x4*)(row + v * 1024 + t * 4));
  vals[9] = (f32x4){0.f, 0.f, 0.f, 0.f};
  if (t < 196) vals[9] = __builtin_nontemporal_load((const f32x4*)(row + 9216 + t * 4));

  int cnt = 0;
  #pragma unroll
  for (int v = 0; v < 10; v++)
    cnt += (vals[v].x != 0.f) + (vals[v].y != 0.f) + (vals[v].z != 0.f) + (vals[v].w != 0.f);

  // wave shfl-scan + one cross-wave LDS step -> deterministic compaction order
  int incl = cnt;
  #pragma unroll
  for (int d = 1; d < 64; d <<= 1){
    int u = __shfl_up(incl, d, 64);
    if (lane >= d) incl += u;
  }
  if (lane == 63) swave[w] = incl;
  __syncthreads();
  int woff = 0, total = 0;
  #pragma unroll
  for (int i = 0; i < 4; i++){
    int s = swave[i];
    total += s;
    if (i < w) woff += s;
  }
  int pos = woff + incl - cnt;          // exclusive prefix

  #pragma unroll
  for (int v = 0; v < 10; v++){
    float q[4] = {vals[v].x, vals[v].y, vals[v].z, vals[v].w};
    #pragma unroll
    for (int e = 0; e < 4; e++){
      if (q[e] != 0.f && pos < CAP){
        pja[(size_t)r * CAP + pos] = (i32x2){(v * 1024 + t * 4 + e) << 8, __float_as_int(q[e])};
        pos++;
      }
    }
  }
  if (t == 0) row_nnz[r] = min(total, CAP);
}

// ---- agg1: one WAVE per row-half (unchanged from R8) ----
__launch_bounds__(256)
__global__ void k_agg1(const int* __restrict__ row_nnz, const i32x2* __restrict__ pja,
                       const ushort* __restrict__ xw1_lo, const ushort* __restrict__ xw1_hi,
                       const float* __restrict__ b1, ushort* __restrict__ Hb){
  const int half = blockIdx.x & 1;
  const int r0   = (blockIdx.x >> 1) * 16;
  const int t = threadIdx.x;
  __shared__ i32x2 sl[16][CAP];   // 16 KB
  __shared__ int   sn[16];
  if (t < 16) sn[t] = row_nnz[r0 + t];
  #pragma unroll
  for (int e = 0; e < 8; e++){
    int idx = t + e * 256;
    int rr = idx >> 7, kk = idx & (CAP - 1);
    sl[rr][kk] = pja[(size_t)(r0 + rr) * CAP + kk];
  }
  __syncthreads();

  const int wv = t >> 6, lane = t & 63;
  const char* table = (const char*)(half ? xw1_hi : xw1_lo);
  const float bias0 = b1[half * 128 + lane * 2 + 0];
  const float bias1 = b1[half * 128 + lane * 2 + 1];

  #pragma unroll
  for (int rr = wv; rr < 16; rr += 4){
    const int n = sn[rr];
    float a0 = 0.f, a1 = 0.f;
    for (int k = 0; k < n; k++){
      i32x2 p = sl[rr][k];
      uint pk = *(const uint*)(table + p.x + lane * 4);
      float a = __int_as_float(p.y);
      a0 += a * bf2f((ushort)(pk & 0xffff));
      a1 += a * bf2f((ushort)(pk >> 16));
    }
    uint o = ((uint)f2bf(fmaxf(a1 + bias1, 0.f)) << 16) | (uint)f2bf(fmaxf(a0 + bias0, 0.f));
    *(uint*)(Hb + (size_t)(r0 + rr) * NHID + half * 128 + lane * 2) = o;
  }
}

// ---- gemm2: HW2b = Hb @ W2t^T (unchanged from R8) ----
__launch_bounds__(256)
__global__ void k_gemm2(const ushort* __restrict__ A, const ushort* __restrict__ Bt,
                        ushort* __restrict__ C){
  const int lane = threadIdx.x & 63;
  const int w    = threadIdx.x >> 6;
  const int wr   = w >> 1, wc = w & 1;
  const int r16  = lane & 15;
  const int kg   = lane >> 4;
  const int row0 = blockIdx.x * 64 + wr * 32;
  const int col0 = blockIdx.y * 64 + wc * 32;

  int arow[2], bcol[2];
  #pragma unroll
  for (int r = 0; r < 2; r++){
    int ar = row0 + r * 16 + r16;
    arow[r] = (ar >= N_NODES) ? (N_NODES - 1) : ar;
  }
  #pragma unroll
  for (int c = 0; c < 2; c++) bcol[c] = col0 + c * 16 + r16;

  f32x4 acc[2][2];
  #pragma unroll
  for (int r = 0; r < 2; r++)
    #pragma unroll
    for (int c = 0; c < 2; c++)
      acc[r][c] = (f32x4){0.f, 0.f, 0.f, 0.f};

  bf16x8 aA[2], bA[2], aB[2], bB[2];
  auto LOADF = [&](bf16x8* a, bf16x8* bb, int k0){
    #pragma unroll
    for (int r = 0; r < 2; r++)
      a[r] = *(const bf16x8*)(A + (size_t)arow[r] * NHID + k0 + kg * 8);
    #pragma unroll
    for (int c = 0; c < 2; c++)
      bb[c] = *(const bf16x8*)(Bt + (size_t)bcol[c] * NHID + k0 + kg * 8);
  };
  auto MM = [&](bf16x8* a, bf16x8* bb){
    #pragma unroll
    for (int r = 0; r < 2; r++)
      #pragma unroll
      for (int c = 0; c < 2; c++)
        acc[r][c] = __builtin_amdgcn_mfma_f32_16x16x32_bf16(a[r], bb[c], acc[r][c], 0, 0, 0);
  };

  LOADF(aA, bA, 0);
  #pragma unroll
  for (int k0 = 0; k0 < NHID; k0 += 64){
    if (k0 + 32 < NHID) LOADF(aB, bB, k0 + 32);
    MM(aA, bA);
    if (k0 + 64 < NHID) LOADF(aA, bA, k0 + 64);
    if (k0 + 32 < NHID) MM(aB, bB);
  }

  #pragma unroll
  for (int r = 0; r < 2; r++)
    #pragma unroll
    for (int c = 0; c < 2; c++){
      int col = col0 + c * 16 + r16;
      #pragma unroll
      for (int i = 0; i < 4; i++){
        int row = row0 + r * 16 + kg * 4 + i;
        if (row < N_NODES) C[(size_t)row * NHID2 + col] = f2bf(acc[r][c][i]);
      }
    }
}

// ---- agg2: one wave per row (unchanged from R8) ----
__launch_bounds__(256)
__global__ void k_agg2(const int* __restrict__ row_nnz, const i32x2* __restrict__ pja,
                       const ushort* __restrict__ hw2b, const float* __restrict__ b2,
                       float* __restrict__ out){
  const int r0 = blockIdx.x * 8;
  const int t = threadIdx.x;
  __shared__ i32x2 sl[8][CAP];    // 8 KB
  __shared__ int   sn[8];
  if (t < 8) sn[t] = row_nnz[r0 + t];
  #pragma unroll
  for (int e = 0; e < 4; e++){
    int idx = t + e * 256;
    int rr = idx >> 7, kk = idx & (CAP - 1);
    sl[rr][kk] = pja[(size_t)(r0 + rr) * CAP + kk];
  }
  __syncthreads();

  const int wv = t >> 6, lane = t & 63;
  const char* table = (const char*)hw2b;
  const float bias0 = b2[lane * 2 + 0];
  const float bias1 = b2[lane * 2 + 1];

  #pragma unroll
  for (int rr = wv; rr < 8; rr += 4){
    const int n = sn[rr];
    float a0 = 0.f, a1 = 0.f;
    for (int k = 0; k < n; k++){
      i32x2 p = sl[rr][k];
      uint pk = *(const uint*)(table + p.x + lane * 4);
      float a = __int_as_float(p.y);
      a0 += a * bf2f((ushort)(pk & 0xffff));
      a1 += a * bf2f((ushort)(pk >> 16));
    }
    float2 o = make_float2(fmaxf(a0 + bias0, 0.f), fmaxf(a1 + bias1, 0.f));
    *(float2*)(out + (size_t)(r0 + rr) * NHID2 + lane * 2) = o;
  }
}

extern "C" void kernel_launch(void* const* d_in, const int* in_sizes, int n_in,
                              void* d_out, int out_size, void* d_ws, size_t ws_size,
                              hipStream_t stream){
  const float* x   = (const float*)d_in[0];
  const float* adj = (const float*)d_in[1];
  const float* W1  = (const float*)d_in[2];
  const float* b1  = (const float*)d_in[3];
  const float* W2  = (const float*)d_in[4];
  const float* b2  = (const float*)d_in[5];
  float* out = (float*)d_out;
  char*  ws  = (char*)d_ws;

  ushort* xb     = (ushort*)(ws);              // x bf16:      10,240,000
  ushort* w1t    = (ushort*)(ws + 10240000);   // W1t bf16:       262,144
  ushort* w2t    = (ushort*)(ws + 10502144);   // W2t bf16:        65,536
  ushort* xw1_lo = (ushort*)(ws + 10567680);   // XW1 lo bf16:  2,560,000
  ushort* xw1_hi = (ushort*)(ws + 13127680);   // XW1 hi bf16:  2,560,000
  ushort* Hb     = (ushort*)(ws + 15687680);   // H bf16:       5,120,000
  ushort* hw2b   = (ushort*)(ws + 20807680);   // HW2 bf16:     2,560,000
  int*    nnz    = (int*)(ws + 23367680);      // 40,000
  i32x2*  pja    = (i32x2*)(ws + 23407680);    // packed (j<<8, a): 10,240,000

  k_cvt<<<5640, 256, 0, stream>>>(x, W1, W2, xb, w1t, w2t);
  k_scan_gemm1<<<10628, 256, 0, stream>>>(adj, xb, w1t, xw1_lo, xw1_hi, nnz, pja);

  // ===== R9 MEASUREMENT PROBE: downstream kernels launched twice (idempotent).
  // dur(R9) - dur(R8=142.3) = dur(agg1)+dur(gemm2)+dur(agg2) + 3 graph gaps. =====
  k_agg1<<<1250, 256, 0, stream>>>(nnz, pja, xw1_lo, xw1_hi, b1, Hb);
  k_agg1<<<1250, 256, 0, stream>>>(nnz, pja, xw1_lo, xw1_hi, b1, Hb);
  k_gemm2<<<dim3(157, 2), 256, 0, stream>>>(Hb, w2t, hw2b);
  k_gemm2<<<dim3(157, 2), 256, 0, stream>>>(Hb, w2t, hw2b);
  k_agg2<<<1250, 256, 0, stream>>>(nnz, pja, hw2b, b2, out);
  k_agg2<<<1250, 256, 0, stream>>>(nnz, pja, hw2b, b2, out);
}

// Round 10
// 150.040 us; speedup vs baseline: 1.2324x; 1.2324x over previous
//
#include <hip/hip_runtime.h>

#define N_NODES 10000
#define NFEAT   512
#define NHID    256
#define NHID2   128
#define CAP     128   // per row: 2 halves x 64 slots; B(5000,.005) mean 25, sd 5 -> 64 is 7.8 sigma

typedef __attribute__((ext_vector_type(8))) short bf16x8;
typedef __attribute__((ext_vector_type(4))) float f32x4;
typedef __attribute__((ext_vector_type(2))) int   i32x2;

__device__ __forceinline__ ushort f2bf(float f){
  union { float f; unsigned u; } v; v.f = f;
  unsigned r = v.u + 0x7FFFu + ((v.u >> 16) & 1u);   // round-to-nearest-even
  return (ushort)(r >> 16);
}
__device__ __forceinline__ float bf2f(ushort u){
  union { unsigned u; float f; } v; v.u = ((unsigned)u) << 16; return v.f;
}

// ---- K0: bf16 converts (x -> xb, W1 -> W1t, W2 -> W2t) ----
__global__ void k_cvt(const float* __restrict__ x, const float* __restrict__ W1,
                      const float* __restrict__ W2, ushort* __restrict__ xb,
                      ushort* __restrict__ w1t, ushort* __restrict__ w2t){
  const int b = blockIdx.x, t = threadIdx.x;
  if (b < 5000){                       // x: 4 elems/thread, exact grid
    int i = (b * 256 + t) * 4;
    float4 q = *(const float4*)(x + i);
    ushort4 o; o.x = f2bf(q.x); o.y = f2bf(q.y); o.z = f2bf(q.z); o.w = f2bf(q.w);
    *(ushort4*)(xb + i) = o;
  } else if (b < 5512){                // W1t[n][k] = W1[k][n]
    int id = (b - 5000) * 256 + t;
    int n = id >> 9, k = id & 511;
    w1t[id] = f2bf(W1[k * NHID + n]);
  } else {                             // W2t[n][k] = W2[k][n]
    int id = (b - 5512) * 256 + t;
    int n = id >> 8, k = id & 255;
    w2t[id] = f2bf(W2[k * NHID2 + n]);
  }
}

// ---- K1: gemm1 (blocks 0..627, single-buffered/low-VGPR) + HALF-ROW adj scan
// (blocks 628..20627). Each half-row block: 20KB register cache, own 64-slot
// list segment (zero-filled to 64 -> padded slots are safe: j=0,a=0). ----
__launch_bounds__(256)
__global__ void k_scan_gemm1(const float* __restrict__ adj, const ushort* __restrict__ xb,
                             const ushort* __restrict__ w1t, ushort* __restrict__ xw1_lo,
                             ushort* __restrict__ xw1_hi, int* __restrict__ nnzh,
                             i32x2* __restrict__ pja){
  const int b = blockIdx.x, t = threadIdx.x;
  const int lane = t & 63, w = t >> 6;

  if (b < 628){
    // ---- gemm1: 64x64 tile, WR=WC=2, K=512, single-buffered (low VGPR) ----
    const int bx = b % 157, by = b / 157;
    const int wr = w >> 1, wc = w & 1;
    const int r16 = lane & 15, kg = lane >> 4;
    const int row0 = bx * 64 + wr * 32;
    const int col0 = by * 64 + wc * 32;

    int arow[2], bcol[2];
    #pragma unroll
    for (int r = 0; r < 2; r++){
      int ar = row0 + r * 16 + r16;
      arow[r] = (ar >= N_NODES) ? (N_NODES - 1) : ar;
    }
    #pragma unroll
    for (int c = 0; c < 2; c++) bcol[c] = col0 + c * 16 + r16;

    f32x4 acc[2][2];
    #pragma unroll
    for (int r = 0; r < 2; r++)
      #pragma unroll
      for (int c = 0; c < 2; c++)
        acc[r][c] = (f32x4){0.f, 0.f, 0.f, 0.f};

    #pragma unroll 4
    for (int k0 = 0; k0 < NFEAT; k0 += 32){
      bf16x8 a[2], bb[2];
      #pragma unroll
      for (int r = 0; r < 2; r++)
        a[r] = *(const bf16x8*)(xb + (size_t)arow[r] * NFEAT + k0 + kg * 8);
      #pragma unroll
      for (int c = 0; c < 2; c++)
        bb[c] = *(const bf16x8*)(w1t + (size_t)bcol[c] * NFEAT + k0 + kg * 8);
      #pragma unroll
      for (int r = 0; r < 2; r++)
        #pragma unroll
        for (int c = 0; c < 2; c++)
          acc[r][c] = __builtin_amdgcn_mfma_f32_16x16x32_bf16(a[r], bb[c], acc[r][c], 0, 0, 0);
    }

    ushort* dst = (by < 2) ? xw1_lo : xw1_hi;
    const int cbase = (by < 2) ? 0 : 128;
    #pragma unroll
    for (int r = 0; r < 2; r++)
      #pragma unroll
      for (int c = 0; c < 2; c++){
        int col = col0 + c * 16 + r16 - cbase;
        #pragma unroll
        for (int i = 0; i < 4; i++){
          int row = row0 + r * 16 + kg * 4 + i;
          if (row < N_NODES) dst[(size_t)row * 128 + col] = f2bf(acc[r][c][i]);
        }
      }
    return;
  }

  // ---- scan path: half-row (5000 elems), register cache = 5 x f32x4 ----
  const int s = b - 628;
  const int r = s >> 1, half = s & 1;
  const float* row = adj + (size_t)r * N_NODES + half * 5000;
  __shared__ int swave[4];

  f32x4 vals[5];
  #pragma unroll
  for (int v = 0; v < 4; v++)
    vals[v] = __builtin_nontemporal_load((const f32x4*)(row + v * 1024 + t * 4));
  vals[4] = (f32x4){0.f, 0.f, 0.f, 0.f};
  if (t < 226) vals[4] = __builtin_nontemporal_load((const f32x4*)(row + 4096 + t * 4));

  int cnt = 0;
  #pragma unroll
  for (int v = 0; v < 5; v++)
    cnt += (vals[v].x != 0.f) + (vals[v].y != 0.f) + (vals[v].z != 0.f) + (vals[v].w != 0.f);

  // wave shfl-scan + one cross-wave LDS step -> deterministic j-ascending order
  int incl = cnt;
  #pragma unroll
  for (int d = 1; d < 64; d <<= 1){
    int u = __shfl_up(incl, d, 64);
    if (lane >= d) incl += u;
  }
  if (lane == 63) swave[w] = incl;
  __syncthreads();
  int woff = 0, total = 0;
  #pragma unroll
  for (int i = 0; i < 4; i++){
    int sv = swave[i];
    total += sv;
    if (i < w) woff += sv;
  }
  int pos = woff + incl - cnt;          // 0-based within this half's 64 slots

  const size_t slot0 = (size_t)r * CAP + half * 64;
  const int jbase = half * 5000;
  #pragma unroll
  for (int v = 0; v < 5; v++){
    float q[4] = {vals[v].x, vals[v].y, vals[v].z, vals[v].w};
    int ebase = jbase + ((v < 4) ? (v * 1024 + t * 4) : (4096 + t * 4));
    #pragma unroll
    for (int e = 0; e < 4; e++){
      if (q[e] != 0.f && pos < 64){
        pja[slot0 + pos] = (i32x2){(ebase + e) << 8, __float_as_int(q[e])};
        pos++;
      }
    }
  }
  // zero-fill unused slots -> padded gather iterations are safe (j=0, a=0)
  for (int z = total + t; z < 64; z += 256)
    pja[slot0 + z] = (i32x2){0, 0};
  if (t == 0) nnzh[s] = min(total, 64);
}

// ---- agg1: one WAVE per row-half-output; branch-free dual-segment gather.
// 1250 blocks: half=bid&1 picks the L2-resident 2.5MB table (XCD parity);
// 16 rows/block; wave handles 4 rows; both list segments jammed (zero-padded). ----
__launch_bounds__(256)
__global__ void k_agg1(const int* __restrict__ nnzh, const i32x2* __restrict__ pja,
                       const ushort* __restrict__ xw1_lo, const ushort* __restrict__ xw1_hi,
                       const float* __restrict__ b1, ushort* __restrict__ Hb){
  const int half = blockIdx.x & 1;
  const int r0   = (blockIdx.x >> 1) * 16;
  const int t = threadIdx.x;
  __shared__ i32x2 sl[16][CAP];   // 16 KB
  __shared__ int   sn[32];        // 16 rows x 2 halves
  if (t < 32) sn[t] = nnzh[r0 * 2 + t];
  #pragma unroll
  for (int e = 0; e < 8; e++){
    int idx = t + e * 256;
    int rr = idx >> 7, kk = idx & (CAP - 1);
    sl[rr][kk] = pja[(size_t)(r0 + rr) * CAP + kk];
  }
  __syncthreads();

  const int wv = t >> 6, lane = t & 63;
  const char* table = (const char*)(half ? xw1_hi : xw1_lo);
  const float bias0 = b1[half * 128 + lane * 2 + 0];
  const float bias1 = b1[half * 128 + lane * 2 + 1];

  #pragma unroll
  for (int rr = wv; rr < 16; rr += 4){
    const int n0 = sn[rr * 2], n1 = sn[rr * 2 + 1];
    const int mp = (max(n0, n1) + 3) & ~3;   // common padded count (zero-slots safe)
    float a0 = 0.f, a1 = 0.f;
    for (int k = 0; k < mp; k += 2){
      #pragma unroll
      for (int u = 0; u < 2; u++){
        i32x2 p = sl[rr][k + u];             // half0 segment
        uint pk = *(const uint*)(table + p.x + lane * 4);
        float a = __int_as_float(p.y);
        a0 += a * bf2f((ushort)(pk & 0xffff));
        a1 += a * bf2f((ushort)(pk >> 16));
        i32x2 p2 = sl[rr][64 + k + u];       // half1 segment
        uint pk2 = *(const uint*)(table + p2.x + lane * 4);
        float a2 = __int_as_float(p2.y);
        a0 += a2 * bf2f((ushort)(pk2 & 0xffff));
        a1 += a2 * bf2f((ushort)(pk2 >> 16));
      }
    }
    uint o = ((uint)f2bf(fmaxf(a1 + bias1, 0.f)) << 16) | (uint)f2bf(fmaxf(a0 + bias0, 0.f));
    *(uint*)(Hb + (size_t)(r0 + rr) * NHID + half * 128 + lane * 2) = o;
  }
}

// ---- gemm2: HW2b = Hb @ W2t^T (M=10000, K=256, N=128), 64x64 tiles ----
__launch_bounds__(256)
__global__ void k_gemm2(const ushort* __restrict__ A, const ushort* __restrict__ Bt,
                        ushort* __restrict__ C){
  const int lane = threadIdx.x & 63;
  const int w    = threadIdx.x >> 6;
  const int wr   = w >> 1, wc = w & 1;
  const int r16  = lane & 15;
  const int kg   = lane >> 4;
  const int row0 = blockIdx.x * 64 + wr * 32;
  const int col0 = blockIdx.y * 64 + wc * 32;

  int arow[2], bcol[2];
  #pragma unroll
  for (int r = 0; r < 2; r++){
    int ar = row0 + r * 16 + r16;
    arow[r] = (ar >= N_NODES) ? (N_NODES - 1) : ar;
  }
  #pragma unroll
  for (int c = 0; c < 2; c++) bcol[c] = col0 + c * 16 + r16;

  f32x4 acc[2][2];
  #pragma unroll
  for (int r = 0; r < 2; r++)
    #pragma unroll
    for (int c = 0; c < 2; c++)
      acc[r][c] = (f32x4){0.f, 0.f, 0.f, 0.f};

  #pragma unroll 4
  for (int k0 = 0; k0 < NHID; k0 += 32){
    bf16x8 a[2], bb[2];
    #pragma unroll
    for (int r = 0; r < 2; r++)
      a[r] = *(const bf16x8*)(A + (size_t)arow[r] * NHID + k0 + kg * 8);
    #pragma unroll
    for (int c = 0; c < 2; c++)
      bb[c] = *(const bf16x8*)(Bt + (size_t)bcol[c] * NHID + k0 + kg * 8);
    #pragma unroll
    for (int r = 0; r < 2; r++)
      #pragma unroll
      for (int c = 0; c < 2; c++)
        acc[r][c] = __builtin_amdgcn_mfma_f32_16x16x32_bf16(a[r], bb[c], acc[r][c], 0, 0, 0);
  }

  #pragma unroll
  for (int r = 0; r < 2; r++)
    #pragma unroll
    for (int c = 0; c < 2; c++){
      int col = col0 + c * 16 + r16;
      #pragma unroll
      for (int i = 0; i < 4; i++){
        int row = row0 + r * 16 + kg * 4 + i;
        if (row < N_NODES) C[(size_t)row * NHID2 + col] = f2bf(acc[r][c][i]);
      }
    }
}

// ---- agg2: one wave per row; hw2b (2.5MB bf16) L2-resident everywhere.
// 1250 blocks x 8 rows; wave handles 2 rows; branch-free dual-segment gather. ----
__launch_bounds__(256)
__global__ void k_agg2(const int* __restrict__ nnzh, const i32x2* __restrict__ pja,
                       const ushort* __restrict__ hw2b, const float* __restrict__ b2,
                       float* __restrict__ out){
  const int r0 = blockIdx.x * 8;
  const int t = threadIdx.x;
  __shared__ i32x2 sl[8][CAP];    // 8 KB
  __shared__ int   sn[16];        // 8 rows x 2 halves
  if (t < 16) sn[t] = nnzh[r0 * 2 + t];
  #pragma unroll
  for (int e = 0; e < 4; e++){
    int idx = t + e * 256;
    int rr = idx >> 7, kk = idx & (CAP - 1);
    sl[rr][kk] = pja[(size_t)(r0 + rr) * CAP + kk];
  }
  __syncthreads();

  const int wv = t >> 6, lane = t & 63;
  const char* table = (const char*)hw2b;
  const float bias0 = b2[lane * 2 + 0];
  const float bias1 = b2[lane * 2 + 1];

  #pragma unroll
  for (int rr = wv; rr < 8; rr += 4){
    const int n0 = sn[rr * 2], n1 = sn[rr * 2 + 1];
    const int mp = (max(n0, n1) + 3) & ~3;
    float a0 = 0.f, a1 = 0.f;
    for (int k = 0; k < mp; k += 2){
      #pragma unroll
      for (int u = 0; u < 2; u++){
        i32x2 p = sl[rr][k + u];
        uint pk = *(const uint*)(table + p.x + lane * 4);
        float a = __int_as_float(p.y);
        a0 += a * bf2f((ushort)(pk & 0xffff));
        a1 += a * bf2f((ushort)(pk >> 16));
        i32x2 p2 = sl[rr][64 + k + u];
        uint pk2 = *(const uint*)(table + p2.x + lane * 4);
        float a2 = __int_as_float(p2.y);
        a0 += a2 * bf2f((ushort)(pk2 & 0xffff));
        a1 += a2 * bf2f((ushort)(pk2 >> 16));
      }
    }
    float2 o = make_float2(fmaxf(a0 + bias0, 0.f), fmaxf(a1 + bias1, 0.f));
    *(float2*)(out + (size_t)(r0 + rr) * NHID2 + lane * 2) = o;
  }
}

extern "C" void kernel_launch(void* const* d_in, const int* in_sizes, int n_in,
                              void* d_out, int out_size, void* d_ws, size_t ws_size,
                              hipStream_t stream){
  const float* x   = (const float*)d_in[0];
  const float* adj = (const float*)d_in[1];
  const float* W1  = (const float*)d_in[2];
  const float* b1  = (const float*)d_in[3];
  const float* W2  = (const float*)d_in[4];
  const float* b2  = (const float*)d_in[5];
  float* out = (float*)d_out;
  char*  ws  = (char*)d_ws;

  // workspace layout (8/16B-aligned), total ~33.7 MB
  ushort* xb     = (ushort*)(ws);              // x bf16:      10,240,000
  ushort* w1t    = (ushort*)(ws + 10240000);   // W1t bf16:       262,144
  ushort* w2t    = (ushort*)(ws + 10502144);   // W2t bf16:        65,536
  ushort* xw1_lo = (ushort*)(ws + 10567680);   // XW1 lo bf16:  2,560,000 (L2-resident)
  ushort* xw1_hi = (ushort*)(ws + 13127680);   // XW1 hi bf16:  2,560,000 (L2-resident)
  ushort* Hb     = (ushort*)(ws + 15687680);   // H bf16:       5,120,000
  ushort* hw2b   = (ushort*)(ws + 20807680);   // HW2 bf16:     2,560,000 (L2-resident)
  int*    nnzh   = (int*)(ws + 23367680);      // 20000 x 4 = 80,000
  i32x2*  pja    = (i32x2*)(ws + 23447680);    // packed (j<<8, a): 10,240,000

  // K0: converts
  k_cvt<<<5640, 256, 0, stream>>>(x, W1, W2, xb, w1t, w2t);

  // K1: gemm1 (628 blocks) + half-row adj scan (20000 blocks)
  k_scan_gemm1<<<20628, 256, 0, stream>>>(adj, xb, w1t, xw1_lo, xw1_hi, nnzh, pja);

  // K2: layer-1 aggregate (wave-per-row-half, jammed dual-segment gather)
  k_agg1<<<1250, 256, 0, stream>>>(nnzh, pja, xw1_lo, xw1_hi, b1, Hb);

  // K3: HW2b = Hb @ W2 (64x64 tiles, 314 blocks)
  k_gemm2<<<dim3(157, 2), 256, 0, stream>>>(Hb, w2t, hw2b);

  // K4: layer-2 aggregate
  k_agg2<<<1250, 256, 0, stream>>>(nnzh, pja, hw2b, b2, out);
}

// Round 11
// 145.590 us; speedup vs baseline: 1.2701x; 1.0306x over previous
//
#include <hip/hip_runtime.h>

#define N_NODES 10000
#define NFEAT   512
#define NHID    256
#define NHID2   128
#define CAP     128   // max nnz/row stored; binomial(10000,0.005) mean 50, sd 7 -> 128 is >11 sigma

typedef __attribute__((ext_vector_type(8))) short bf16x8;
typedef __attribute__((ext_vector_type(4))) float f32x4;
typedef __attribute__((ext_vector_type(2))) int   i32x2;

__device__ __forceinline__ ushort f2bf(float f){
  union { float f; unsigned u; } v; v.f = f;
  unsigned r = v.u + 0x7FFFu + ((v.u >> 16) & 1u);   // round-to-nearest-even
  return (ushort)(r >> 16);
}
__device__ __forceinline__ float bf2f(ushort u){
  union { unsigned u; float f; } v; v.u = ((unsigned)u) << 16; return v.f;
}

// ---- K1: adj scan (10000 blocks) with gemm1 blocks INTERLEAVED 1-per-16.
// Dispatch is ~blockIdx-ordered: interleaving keeps the compute-bound gemm
// co-resident with the HBM-bound scan for the whole kernel (R7-R10 put gemm
// at blockIdx 0..627 -> it ran FIRST, serialized ahead of the scan).
// gemm1 reads x/W1 as f32 and converts inline (kills the separate cvt kernel
// and its dependency). xw1 written column-split lo/hi [10000][128] bf16
// (2.5MB each, L2-resident for agg1). List: (j<<8, a) byte-offset pairs. ----
__launch_bounds__(256)
__global__ void k_scan_gemm1(const float* __restrict__ adj, const float* __restrict__ x,
                             const float* __restrict__ W1, ushort* __restrict__ xw1_lo,
                             ushort* __restrict__ xw1_hi, int* __restrict__ row_nnz,
                             i32x2* __restrict__ pja){
  const int b = blockIdx.x, t = threadIdx.x;
  const int lane = t & 63, w = t >> 6;

  int gid = -1, sid = -1;
  if (b >= 10625)            gid = 625 + (b - 10625);   // last 3 gemm blocks
  else if ((b % 17) == 16)   gid = b / 17;              // every 17th block is gemm
  else                       sid = b - b / 17;          // scan ids 0..9999

  if (gid >= 0){
    // ---- gemm1: 64x64 tile, WR=WC=2, K=512, inline f32->bf16 cvt ----
    const int bx = gid % 157, by = gid / 157;           // by 0..3
    const int wr = w >> 1, wc = w & 1;
    const int r16 = lane & 15, kg = lane >> 4;
    const int row0 = bx * 64 + wr * 32;
    const int col0 = by * 64 + wc * 32;

    int arow[2], bcol[2];
    #pragma unroll
    for (int r = 0; r < 2; r++){
      int ar = row0 + r * 16 + r16;
      arow[r] = (ar >= N_NODES) ? (N_NODES - 1) : ar;   // clamp; store masked later
    }
    #pragma unroll
    for (int c = 0; c < 2; c++) bcol[c] = col0 + c * 16 + r16;

    f32x4 acc[2][2];
    #pragma unroll
    for (int r = 0; r < 2; r++)
      #pragma unroll
      for (int c = 0; c < 2; c++)
        acc[r][c] = (f32x4){0.f, 0.f, 0.f, 0.f};

    for (int k0 = 0; k0 < NFEAT; k0 += 32){
      bf16x8 a[2], bb[2];
      #pragma unroll
      for (int r = 0; r < 2; r++){
        const float* src = x + (size_t)arow[r] * NFEAT + k0 + kg * 8;
        f32x4 u0 = *(const f32x4*)(src);
        f32x4 u1 = *(const f32x4*)(src + 4);
        a[r][0] = f2bf(u0.x); a[r][1] = f2bf(u0.y); a[r][2] = f2bf(u0.z); a[r][3] = f2bf(u0.w);
        a[r][4] = f2bf(u1.x); a[r][5] = f2bf(u1.y); a[r][6] = f2bf(u1.z); a[r][7] = f2bf(u1.w);
      }
      #pragma unroll
      for (int c = 0; c < 2; c++){
        const float* src = W1 + (size_t)(k0 + kg * 8) * NHID + bcol[c];
        #pragma unroll
        for (int j = 0; j < 8; j++) bb[c][j] = f2bf(src[j * NHID]);   // stride-NHID (L2/L3-hot)
      }
      #pragma unroll
      for (int r = 0; r < 2; r++)
        #pragma unroll
        for (int c = 0; c < 2; c++)
          acc[r][c] = __builtin_amdgcn_mfma_f32_16x16x32_bf16(a[r], bb[c], acc[r][c], 0, 0, 0);
    }

    ushort* dst = (by < 2) ? xw1_lo : xw1_hi;
    const int cbase = (by < 2) ? 0 : 128;
    #pragma unroll
    for (int r = 0; r < 2; r++)
      #pragma unroll
      for (int c = 0; c < 2; c++){
        int col = col0 + c * 16 + r16 - cbase;
        #pragma unroll
        for (int i = 0; i < 4; i++){
          int row = row0 + r * 16 + kg * 4 + i;
          if (row < N_NODES) dst[(size_t)row * 128 + col] = f2bf(acc[r][c][i]);
        }
      }
    return;
  }

  // ---- scan path: row sid, single nontemporal pass, register-cached (R8) ----
  const int r = sid;
  const float* row = adj + (size_t)r * N_NODES;
  __shared__ int swave[4];

  f32x4 vals[10];
  #pragma unroll
  for (int v = 0; v < 9; v++)
    vals[v] = __builtin_nontemporal_load((const f32x4*)(row + v * 1024 + t * 4));
  vals[9] = (f32x4){0.f, 0.f, 0.f, 0.f};
  if (t < 196) vals[9] = __builtin_nontemporal_load((const f32x4*)(row + 9216 + t * 4));

  int cnt = 0;
  #pragma unroll
  for (int v = 0; v < 10; v++)
    cnt += (vals[v].x != 0.f) + (vals[v].y != 0.f) + (vals[v].z != 0.f) + (vals[v].w != 0.f);

  // wave shfl-scan + one cross-wave LDS step -> deterministic j-ascending order
  int incl = cnt;
  #pragma unroll
  for (int d = 1; d < 64; d <<= 1){
    int u = __shfl_up(incl, d, 64);
    if (lane >= d) incl += u;
  }
  if (lane == 63) swave[w] = incl;
  __syncthreads();
  int woff = 0, total = 0;
  #pragma unroll
  for (int i = 0; i < 4; i++){
    int s = swave[i];
    total += s;
    if (i < w) woff += s;
  }
  int pos = woff + incl - cnt;          // exclusive prefix

  #pragma unroll
  for (int v = 0; v < 10; v++){
    float q[4] = {vals[v].x, vals[v].y, vals[v].z, vals[v].w};
    #pragma unroll
    for (int e = 0; e < 4; e++){
      if (q[e] != 0.f && pos < CAP){
        pja[(size_t)r * CAP + pos] = (i32x2){(v * 1024 + t * 4 + e) << 8, __float_as_int(q[e])};
        pos++;
      }
    }
  }
  if (t == 0) row_nnz[r] = min(total, CAP);
}

// ---- agg1: one WAVE per row-half (exact R8 structure).
// 1250 blocks: half=bid&1 picks the L2-resident 2.5MB table (XCD parity);
// 16 rows/block; wave handles 4 row-halves. ----
__launch_bounds__(256)
__global__ void k_agg1(const int* __restrict__ row_nnz, const i32x2* __restrict__ pja,
                       const ushort* __restrict__ xw1_lo, const ushort* __restrict__ xw1_hi,
                       const float* __restrict__ b1, ushort* __restrict__ Hb){
  const int half = blockIdx.x & 1;
  const int r0   = (blockIdx.x >> 1) * 16;
  const int t = threadIdx.x;
  __shared__ i32x2 sl[16][CAP];   // 16 KB
  __shared__ int   sn[16];
  if (t < 16) sn[t] = row_nnz[r0 + t];
  #pragma unroll
  for (int e = 0; e < 8; e++){
    int idx = t + e * 256;
    int rr = idx >> 7, kk = idx & (CAP - 1);
    sl[rr][kk] = pja[(size_t)(r0 + rr) * CAP + kk];
  }
  __syncthreads();

  const int wv = t >> 6, lane = t & 63;
  const char* table = (const char*)(half ? xw1_hi : xw1_lo);
  const float bias0 = b1[half * 128 + lane * 2 + 0];
  const float bias1 = b1[half * 128 + lane * 2 + 1];

  #pragma unroll
  for (int rr = wv; rr < 16; rr += 4){
    const int n = sn[rr];
    float a0 = 0.f, a1 = 0.f;
    for (int k = 0; k < n; k++){
      i32x2 p = sl[rr][k];                 // LDS broadcast
      uint pk = *(const uint*)(table + p.x + lane * 4);   // 2 bf16 cols
      float a = __int_as_float(p.y);
      a0 += a * bf2f((ushort)(pk & 0xffff));
      a1 += a * bf2f((ushort)(pk >> 16));
    }
    uint o = ((uint)f2bf(fmaxf(a1 + bias1, 0.f)) << 16) | (uint)f2bf(fmaxf(a0 + bias0, 0.f));
    *(uint*)(Hb + (size_t)(r0 + rr) * NHID + half * 128 + lane * 2) = o;
  }
}

// ---- gemm2: HW2b = Hb @ W2 (M=10000, K=256, N=128), inline f32->bf16 of W2 ----
__launch_bounds__(256)
__global__ void k_gemm2(const ushort* __restrict__ A, const float* __restrict__ W2,
                        ushort* __restrict__ C){
  const int lane = threadIdx.x & 63;
  const int w    = threadIdx.x >> 6;
  const int wr   = w >> 1, wc = w & 1;
  const int r16  = lane & 15;
  const int kg   = lane >> 4;
  const int row0 = blockIdx.x * 64 + wr * 32;
  const int col0 = blockIdx.y * 64 + wc * 32;

  int arow[2], bcol[2];
  #pragma unroll
  for (int r = 0; r < 2; r++){
    int ar = row0 + r * 16 + r16;
    arow[r] = (ar >= N_NODES) ? (N_NODES - 1) : ar;
  }
  #pragma unroll
  for (int c = 0; c < 2; c++) bcol[c] = col0 + c * 16 + r16;

  f32x4 acc[2][2];
  #pragma unroll
  for (int r = 0; r < 2; r++)
    #pragma unroll
    for (int c = 0; c < 2; c++)
      acc[r][c] = (f32x4){0.f, 0.f, 0.f, 0.f};

  for (int k0 = 0; k0 < NHID; k0 += 32){
    bf16x8 a[2], bb[2];
    #pragma unroll
    for (int r = 0; r < 2; r++)
      a[r] = *(const bf16x8*)(A + (size_t)arow[r] * NHID + k0 + kg * 8);
    #pragma unroll
    for (int c = 0; c < 2; c++){
      const float* src = W2 + (size_t)(k0 + kg * 8) * NHID2 + bcol[c];
      #pragma unroll
      for (int j = 0; j < 8; j++) bb[c][j] = f2bf(src[j * NHID2]);  // stride-NHID2 (L2-hot)
    }
    #pragma unroll
    for (int r = 0; r < 2; r++)
      #pragma unroll
      for (int c = 0; c < 2; c++)
        acc[r][c] = __builtin_amdgcn_mfma_f32_16x16x32_bf16(a[r], bb[c], acc[r][c], 0, 0, 0);
  }

  #pragma unroll
  for (int r = 0; r < 2; r++)
    #pragma unroll
    for (int c = 0; c < 2; c++){
      int col = col0 + c * 16 + r16;
      #pragma unroll
      for (int i = 0; i < 4; i++){
        int row = row0 + r * 16 + kg * 4 + i;
        if (row < N_NODES) C[(size_t)row * NHID2 + col] = f2bf(acc[r][c][i]);
      }
    }
}

// ---- agg2: one wave per row (exact R8 structure); hw2b 2.5MB L2-resident ----
__launch_bounds__(256)
__global__ void k_agg2(const int* __restrict__ row_nnz, const i32x2* __restrict__ pja,
                       const ushort* __restrict__ hw2b, const float* __restrict__ b2,
                       float* __restrict__ out){
  const int r0 = blockIdx.x * 8;
  const int t = threadIdx.x;
  __shared__ i32x2 sl[8][CAP];    // 8 KB
  __shared__ int   sn[8];
  if (t < 8) sn[t] = row_nnz[r0 + t];
  #pragma unroll
  for (int e = 0; e < 4; e++){
    int idx = t + e * 256;
    int rr = idx >> 7, kk = idx & (CAP - 1);
    sl[rr][kk] = pja[(size_t)(r0 + rr) * CAP + kk];
  }
  __syncthreads();

  const int wv = t >> 6, lane = t & 63;
  const char* table = (const char*)hw2b;
  const float bias0 = b2[lane * 2 + 0];
  const float bias1 = b2[lane * 2 + 1];

  #pragma unroll
  for (int rr = wv; rr < 8; rr += 4){
    const int n = sn[rr];
    float a0 = 0.f, a1 = 0.f;
    for (int k = 0; k < n; k++){
      i32x2 p = sl[rr][k];
      uint pk = *(const uint*)(table + p.x + lane * 4);
      float a = __int_as_float(p.y);
      a0 += a * bf2f((ushort)(pk & 0xffff));
      a1 += a * bf2f((ushort)(pk >> 16));
    }
    float2 o = make_float2(fmaxf(a0 + bias0, 0.f), fmaxf(a1 + bias1, 0.f));
    *(float2*)(out + (size_t)(r0 + rr) * NHID2 + lane * 2) = o;
  }
}

extern "C" void kernel_launch(void* const* d_in, const int* in_sizes, int n_in,
                              void* d_out, int out_size, void* d_ws, size_t ws_size,
                              hipStream_t stream){
  const float* x   = (const float*)d_in[0];
  const float* adj = (const float*)d_in[1];
  const float* W1  = (const float*)d_in[2];
  const float* b1  = (const float*)d_in[3];
  const float* W2  = (const float*)d_in[4];
  const float* b2  = (const float*)d_in[5];
  float* out = (float*)d_out;
  char*  ws  = (char*)d_ws;

  // workspace layout (16B-aligned), total ~23.1 MB
  ushort* xw1_lo = (ushort*)(ws);              // XW1 lo bf16:  2,560,000 (L2-resident)
  ushort* xw1_hi = (ushort*)(ws +  2560000);   // XW1 hi bf16:  2,560,000 (L2-resident)
  ushort* Hb     = (ushort*)(ws +  5120000);   // H bf16:       5,120,000
  ushort* hw2b   = (ushort*)(ws + 10240000);   // HW2 bf16:     2,560,000 (L2-resident)
  int*    nnz    = (int*)(ws + 12800000);      // 40,000
  i32x2*  pja    = (i32x2*)(ws + 12840000);    // packed (j<<8, a): 10,240,000

  // K1: adj scan with gemm1 interleaved 1-per-16 (inline f32->bf16)
  k_scan_gemm1<<<10628, 256, 0, stream>>>(adj, x, W1, xw1_lo, xw1_hi, nnz, pja);

  // K2: layer-1 aggregate (wave-per-row-half)
  k_agg1<<<1250, 256, 0, stream>>>(nnz, pja, xw1_lo, xw1_hi, b1, Hb);

  // K3: HW2b = Hb @ W2 (inline W2 cvt, 314 blocks)
  k_gemm2<<<dim3(157, 2), 256, 0, stream>>>(Hb, W2, hw2b);

  // K4: layer-2 aggregate
  k_agg2<<<1250, 256, 0, stream>>>(nnz, pja, hw2b, b2, out);
}

// Round 12
// 142.103 us; speedup vs baseline: 1.3012x; 1.0245x over previous
//
#include <hip/hip_runtime.h>

#define N_NODES 10000
#define NFEAT   512
#define NHID    256
#define NHID2   128
#define CAP     128   // max nnz/row stored; binomial(10000,0.005) mean 50, sd 7 -> 128 is >11 sigma

typedef __attribute__((ext_vector_type(8))) short bf16x8;
typedef __attribute__((ext_vector_type(4))) float f32x4;
typedef __attribute__((ext_vector_type(2))) int   i32x2;

__device__ __forceinline__ ushort f2bf(float f){
  union { float f; unsigned u; } v; v.f = f;
  unsigned r = v.u + 0x7FFFu + ((v.u >> 16) & 1u);   // round-to-nearest-even
  return (ushort)(r >> 16);
}
__device__ __forceinline__ float bf2f(ushort u){
  union { unsigned u; float f; } v; v.u = ((unsigned)u) << 16; return v.f;
}

// ---- K1: adj scan (blocks 0..9999) + bf16 converts at the TAIL (blocks
// 10000..15639). This exact shape measured standalone at 78.1us (R5 probe):
// the HBM-bound scan hides the convert work; scan path carries no gemm state.
// NO gemm fusion: R8's gemm-first fusion cost ~15us of serialization (ledger:
// K1(R8)=92.7 vs scan+cvt=78.1). gemm1 runs as its own kernel after. ----
__launch_bounds__(256)
__global__ void k_scan_cvt(const float* __restrict__ adj, const float* __restrict__ x,
                           const float* __restrict__ W1, const float* __restrict__ W2,
                           ushort* __restrict__ xb, ushort* __restrict__ w1t,
                           ushort* __restrict__ w2t, int* __restrict__ row_nnz,
                           i32x2* __restrict__ pja){
  const int b = blockIdx.x, t = threadIdx.x;

  if (b >= N_NODES){                    // ---- convert path (tail blocks) ----
    if (b < 15000){                     // x: 4 elems/thread, exact grid
      int i = ((b - N_NODES) * 256 + t) * 4;
      float4 q = *(const float4*)(x + i);
      ushort4 o; o.x = f2bf(q.x); o.y = f2bf(q.y); o.z = f2bf(q.z); o.w = f2bf(q.w);
      *(ushort4*)(xb + i) = o;
    } else if (b < 15512){              // W1t[n][k] = W1[k][n]
      int id = (b - 15000) * 256 + t;
      int n = id >> 9, k = id & 511;
      w1t[id] = f2bf(W1[k * NHID + n]);
    } else {                            // W2t[n][k] = W2[k][n]
      int id = (b - 15512) * 256 + t;
      int n = id >> 8, k = id & 255;
      w2t[id] = f2bf(W2[k * NHID2 + n]);
    }
    return;
  }

  // ---- scan path: row b, single nontemporal pass, register-cached (R8) ----
  const int r = b;
  const int lane = t & 63, w = t >> 6;
  const float* row = adj + (size_t)r * N_NODES;
  __shared__ int swave[4];

  f32x4 vals[10];
  #pragma unroll
  for (int v = 0; v < 9; v++)
    vals[v] = __builtin_nontemporal_load((const f32x4*)(row + v * 1024 + t * 4));
  vals[9] = (f32x4){0.f, 0.f, 0.f, 0.f};
  if (t < 196) vals[9] = __builtin_nontemporal_load((const f32x4*)(row + 9216 + t * 4));

  int cnt = 0;
  #pragma unroll
  for (int v = 0; v < 10; v++)
    cnt += (vals[v].x != 0.f) + (vals[v].y != 0.f) + (vals[v].z != 0.f) + (vals[v].w != 0.f);

  // wave shfl-scan + one cross-wave LDS step -> deterministic j-ascending order
  int incl = cnt;
  #pragma unroll
  for (int d = 1; d < 64; d <<= 1){
    int u = __shfl_up(incl, d, 64);
    if (lane >= d) incl += u;
  }
  if (lane == 63) swave[w] = incl;
  __syncthreads();
  int woff = 0, total = 0;
  #pragma unroll
  for (int i = 0; i < 4; i++){
    int s = swave[i];
    total += s;
    if (i < w) woff += s;
  }
  int pos = woff + incl - cnt;          // exclusive prefix

  #pragma unroll
  for (int v = 0; v < 10; v++){
    float q[4] = {vals[v].x, vals[v].y, vals[v].z, vals[v].w};
    #pragma unroll
    for (int e = 0; e < 4; e++){
      if (q[e] != 0.f && pos < CAP){
        pja[(size_t)r * CAP + pos] = (i32x2){(v * 1024 + t * 4 + e) << 8, __float_as_int(q[e])};
        pos++;
      }
    }
  }
  if (t == 0) row_nnz[r] = min(total, CAP);
}

// ---- K2: gemm1 standalone: XW1 = xb @ w1t^T (M=10000, K=512), 64x64 tiles,
// double-buffered fragments (R8's gemm path). Column-split bf16 output:
// by<2 -> xw1_lo (cols 0..127), else xw1_hi — each 2.5MB, L2-resident for agg1. ----
__launch_bounds__(256)
__global__ void k_gemm1(const ushort* __restrict__ A, const ushort* __restrict__ Bt,
                        ushort* __restrict__ xw1_lo, ushort* __restrict__ xw1_hi){
  const int lane = threadIdx.x & 63;
  const int w    = threadIdx.x >> 6;
  const int wr   = w >> 1, wc = w & 1;
  const int r16  = lane & 15;
  const int kg   = lane >> 4;
  const int row0 = blockIdx.x * 64 + wr * 32;
  const int col0 = blockIdx.y * 64 + wc * 32;

  int arow[2], bcol[2];
  #pragma unroll
  for (int r = 0; r < 2; r++){
    int ar = row0 + r * 16 + r16;
    arow[r] = (ar >= N_NODES) ? (N_NODES - 1) : ar;
  }
  #pragma unroll
  for (int c = 0; c < 2; c++) bcol[c] = col0 + c * 16 + r16;

  f32x4 acc[2][2];
  #pragma unroll
  for (int r = 0; r < 2; r++)
    #pragma unroll
    for (int c = 0; c < 2; c++)
      acc[r][c] = (f32x4){0.f, 0.f, 0.f, 0.f};

  bf16x8 aA[2], bA[2], aB[2], bB[2];
  auto LOADF = [&](bf16x8* a, bf16x8* bb, int k0){
    #pragma unroll
    for (int r = 0; r < 2; r++)
      a[r] = *(const bf16x8*)(A + (size_t)arow[r] * NFEAT + k0 + kg * 8);
    #pragma unroll
    for (int c = 0; c < 2; c++)
      bb[c] = *(const bf16x8*)(Bt + (size_t)bcol[c] * NFEAT + k0 + kg * 8);
  };
  auto MM = [&](bf16x8* a, bf16x8* bb){
    #pragma unroll
    for (int r = 0; r < 2; r++)
      #pragma unroll
      for (int c = 0; c < 2; c++)
        acc[r][c] = __builtin_amdgcn_mfma_f32_16x16x32_bf16(a[r], bb[c], acc[r][c], 0, 0, 0);
  };

  LOADF(aA, bA, 0);
  #pragma unroll
  for (int k0 = 0; k0 < NFEAT; k0 += 64){
    if (k0 + 32 < NFEAT) LOADF(aB, bB, k0 + 32);
    MM(aA, bA);
    if (k0 + 64 < NFEAT) LOADF(aA, bA, k0 + 64);
    if (k0 + 32 < NFEAT) MM(aB, bB);
  }

  ushort* dst = (blockIdx.y < 2) ? xw1_lo : xw1_hi;
  const int cbase = (blockIdx.y < 2) ? 0 : 128;
  #pragma unroll
  for (int r = 0; r < 2; r++)
    #pragma unroll
    for (int c = 0; c < 2; c++){
      int col = col0 + c * 16 + r16 - cbase;
      #pragma unroll
      for (int i = 0; i < 4; i++){
        int row = row0 + r * 16 + kg * 4 + i;
        if (row < N_NODES) dst[(size_t)row * 128 + col] = f2bf(acc[r][c][i]);
      }
    }
}

// ---- agg1: one WAVE per row-half (exact R8). 1250 blocks; half=bid&1 picks
// the L2-resident 2.5MB table; 16 rows/block; wave handles 4 row-halves. ----
__launch_bounds__(256)
__global__ void k_agg1(const int* __restrict__ row_nnz, const i32x2* __restrict__ pja,
                       const ushort* __restrict__ xw1_lo, const ushort* __restrict__ xw1_hi,
                       const float* __restrict__ b1, ushort* __restrict__ Hb){
  const int half = blockIdx.x & 1;
  const int r0   = (blockIdx.x >> 1) * 16;
  const int t = threadIdx.x;
  __shared__ i32x2 sl[16][CAP];   // 16 KB
  __shared__ int   sn[16];
  if (t < 16) sn[t] = row_nnz[r0 + t];
  #pragma unroll
  for (int e = 0; e < 8; e++){
    int idx = t + e * 256;
    int rr = idx >> 7, kk = idx & (CAP - 1);
    sl[rr][kk] = pja[(size_t)(r0 + rr) * CAP + kk];
  }
  __syncthreads();

  const int wv = t >> 6, lane = t & 63;
  const char* table = (const char*)(half ? xw1_hi : xw1_lo);
  const float bias0 = b1[half * 128 + lane * 2 + 0];
  const float bias1 = b1[half * 128 + lane * 2 + 1];

  #pragma unroll
  for (int rr = wv; rr < 16; rr += 4){
    const int n = sn[rr];
    float a0 = 0.f, a1 = 0.f;
    for (int k = 0; k < n; k++){
      i32x2 p = sl[rr][k];                 // LDS broadcast
      uint pk = *(const uint*)(table + p.x + lane * 4);   // 2 bf16 cols
      float a = __int_as_float(p.y);
      a0 += a * bf2f((ushort)(pk & 0xffff));
      a1 += a * bf2f((ushort)(pk >> 16));
    }
    uint o = ((uint)f2bf(fmaxf(a1 + bias1, 0.f)) << 16) | (uint)f2bf(fmaxf(a0 + bias0, 0.f));
    *(uint*)(Hb + (size_t)(r0 + rr) * NHID + half * 128 + lane * 2) = o;
  }
}

// ---- gemm2: HW2b = Hb @ w2t^T (exact R8; M=10000, K=256, N=128) ----
__launch_bounds__(256)
__global__ void k_gemm2(const ushort* __restrict__ A, const ushort* __restrict__ Bt,
                        ushort* __restrict__ C){
  const int lane = threadIdx.x & 63;
  const int w    = threadIdx.x >> 6;
  const int wr   = w >> 1, wc = w & 1;
  const int r16  = lane & 15;
  const int kg   = lane >> 4;
  const int row0 = blockIdx.x * 64 + wr * 32;
  const int col0 = blockIdx.y * 64 + wc * 32;

  int arow[2], bcol[2];
  #pragma unroll
  for (int r = 0; r < 2; r++){
    int ar = row0 + r * 16 + r16;
    arow[r] = (ar >= N_NODES) ? (N_NODES - 1) : ar;
  }
  #pragma unroll
  for (int c = 0; c < 2; c++) bcol[c] = col0 + c * 16 + r16;

  f32x4 acc[2][2];
  #pragma unroll
  for (int r = 0; r < 2; r++)
    #pragma unroll
    for (int c = 0; c < 2; c++)
      acc[r][c] = (f32x4){0.f, 0.f, 0.f, 0.f};

  bf16x8 aA[2], bA[2], aB[2], bB[2];
  auto LOADF = [&](bf16x8* a, bf16x8* bb, int k0){
    #pragma unroll
    for (int r = 0; r < 2; r++)
      a[r] = *(const bf16x8*)(A + (size_t)arow[r] * NHID + k0 + kg * 8);
    #pragma unroll
    for (int c = 0; c < 2; c++)
      bb[c] = *(const bf16x8*)(Bt + (size_t)bcol[c] * NHID + k0 + kg * 8);
  };
  auto MM = [&](bf16x8* a, bf16x8* bb){
    #pragma unroll
    for (int r = 0; r < 2; r++)
      #pragma unroll
      for (int c = 0; c < 2; c++)
        acc[r][c] = __builtin_amdgcn_mfma_f32_16x16x32_bf16(a[r], bb[c], acc[r][c], 0, 0, 0);
  };

  LOADF(aA, bA, 0);
  #pragma unroll
  for (int k0 = 0; k0 < NHID; k0 += 64){
    if (k0 + 32 < NHID) LOADF(aB, bB, k0 + 32);
    MM(aA, bA);
    if (k0 + 64 < NHID) LOADF(aA, bA, k0 + 64);
    if (k0 + 32 < NHID) MM(aB, bB);
  }

  #pragma unroll
  for (int r = 0; r < 2; r++)
    #pragma unroll
    for (int c = 0; c < 2; c++){
      int col = col0 + c * 16 + r16;
      #pragma unroll
      for (int i = 0; i < 4; i++){
        int row = row0 + r * 16 + kg * 4 + i;
        if (row < N_NODES) C[(size_t)row * NHID2 + col] = f2bf(acc[r][c][i]);
      }
    }
}

// ---- agg2: one wave per row (exact R8); hw2b 2.5MB L2-resident ----
__launch_bounds__(256)
__global__ void k_agg2(const int* __restrict__ row_nnz, const i32x2* __restrict__ pja,
                       const ushort* __restrict__ hw2b, const float* __restrict__ b2,
                       float* __restrict__ out){
  const int r0 = blockIdx.x * 8;
  const int t = threadIdx.x;
  __shared__ i32x2 sl[8][CAP];    // 8 KB
  __shared__ int   sn[8];
  if (t < 8) sn[t] = row_nnz[r0 + t];
  #pragma unroll
  for (int e = 0; e < 4; e++){
    int idx = t + e * 256;
    int rr = idx >> 7, kk = idx & (CAP - 1);
    sl[rr][kk] = pja[(size_t)(r0 + rr) * CAP + kk];
  }
  __syncthreads();

  const int wv = t >> 6, lane = t & 63;
  const char* table = (const char*)hw2b;
  const float bias0 = b2[lane * 2 + 0];
  const float bias1 = b2[lane * 2 + 1];

  #pragma unroll
  for (int rr = wv; rr < 8; rr += 4){
    const int n = sn[rr];
    float a0 = 0.f, a1 = 0.f;
    for (int k = 0; k < n; k++){
      i32x2 p = sl[rr][k];
      uint pk = *(const uint*)(table + p.x + lane * 4);
      float a = __int_as_float(p.y);
      a0 += a * bf2f((ushort)(pk & 0xffff));
      a1 += a * bf2f((ushort)(pk >> 16));
    }
    float2 o = make_float2(fmaxf(a0 + bias0, 0.f), fmaxf(a1 + bias1, 0.f));
    *(float2*)(out + (size_t)(r0 + rr) * NHID2 + lane * 2) = o;
  }
}

extern "C" void kernel_launch(void* const* d_in, const int* in_sizes, int n_in,
                              void* d_out, int out_size, void* d_ws, size_t ws_size,
                              hipStream_t stream){
  const float* x   = (const float*)d_in[0];
  const float* adj = (const float*)d_in[1];
  const float* W1  = (const float*)d_in[2];
  const float* b1  = (const float*)d_in[3];
  const float* W2  = (const float*)d_in[4];
  const float* b2  = (const float*)d_in[5];
  float* out = (float*)d_out;
  char*  ws  = (char*)d_ws;

  // workspace layout (16B-aligned), total ~33.6 MB
  ushort* xb     = (ushort*)(ws);              // x bf16:      10,240,000
  ushort* w1t    = (ushort*)(ws + 10240000);   // W1t bf16:       262,144
  ushort* w2t    = (ushort*)(ws + 10502144);   // W2t bf16:        65,536
  ushort* xw1_lo = (ushort*)(ws + 10567680);   // XW1 lo bf16:  2,560,000 (L2-resident)
  ushort* xw1_hi = (ushort*)(ws + 13127680);   // XW1 hi bf16:  2,560,000 (L2-resident)
  ushort* Hb     = (ushort*)(ws + 15687680);   // H bf16:       5,120,000
  ushort* hw2b   = (ushort*)(ws + 20807680);   // HW2 bf16:     2,560,000 (L2-resident)
  int*    nnz    = (int*)(ws + 23367680);      // 40,000
  i32x2*  pja    = (i32x2*)(ws + 23407680);    // packed (j<<8, a): 10,240,000

  // K1: adj scan (10000 blocks) + converts at the tail — measured 78.1us (R5)
  k_scan_cvt<<<15640, 256, 0, stream>>>(adj, x, W1, W2, xb, w1t, w2t, nnz, pja);

  // K2: gemm1 standalone (628 blocks, bf16 operands, ~10us)
  k_gemm1<<<dim3(157, 4), 256, 0, stream>>>(xb, w1t, xw1_lo, xw1_hi);

  // K3: layer-1 aggregate (wave-per-row-half) — R9 probe: downstream trio = 42.6us
  k_agg1<<<1250, 256, 0, stream>>>(nnz, pja, xw1_lo, xw1_hi, b1, Hb);

  // K4: HW2b = Hb @ W2 (64x64 tiles, 314 blocks)
  k_gemm2<<<dim3(157, 2), 256, 0, stream>>>(Hb, w2t, hw2b);

  // K5: layer-2 aggregate
  k_agg2<<<1250, 256, 0, stream>>>(nnz, pja, hw2b, b2, out);
}